// Round 16
// baseline (465.343 us; speedup 1.0000x reference)
//
#include <hip/hip_runtime.h>
#include <hip/hip_bf16.h>

#define NN 2048
#define EE 32768
#define DND 512
#define NH 8
#define HD 64
#define MAXD 128
#define NEGF (-1e30f)
#define BN_SCALE 0.9999950000374997f  // 1/sqrt(1+1e-5)

typedef __attribute__((ext_vector_type(8))) short bf16x8;
typedef __attribute__((ext_vector_type(4))) float f32x4;
typedef unsigned short u16;
typedef unsigned int u32;

static __device__ __forceinline__ float4 ld4(const float* p) {
    return *reinterpret_cast<const float4*>(p);
}
static __device__ __forceinline__ u16 f2b(float f) {
    __hip_bfloat16 h = __float2bfloat16(f);
    return *reinterpret_cast<u16*>(&h);
}
static __device__ __forceinline__ float b2f(u32 bits) {
    return __uint_as_float(bits << 16);
}
static __device__ __forceinline__ void gl_lds(const u16* g, u16* l) {
    __builtin_amdgcn_global_load_lds((const __attribute__((address_space(1))) void*)g,
                                     (__attribute__((address_space(3))) void*)l, 16, 0, 0);
}

// ---------------- consolidated setup kernels ----------------

__global__ __launch_bounds__(256) void setup_init_k(u32* __restrict__ t2,
                                                    int* __restrict__ adj, float* __restrict__ wadj,
                                                    int* __restrict__ cnt,
                                                    int* __restrict__ ocnt, int* __restrict__ icnt,
                                                    u16* __restrict__ zero)
{
    int i = blockIdx.x * 256 + threadIdx.x;
    t2[i] = 0xFFFFFFFFu;
    if (i < NN) {
        cnt[i] = 1; adj[i * MAXD] = i; wadj[i * MAXD] = 1.0f;
        ocnt[i] = 0; icnt[i] = 0;
    }
    if (i < 1024) zero[i] = 0;
}

__global__ __launch_bounds__(256) void fill_scatter_k(const int* __restrict__ ei, u16* __restrict__ t,
                                                      int* __restrict__ oadj, int* __restrict__ ocnt,
                                                      int* __restrict__ iadj, int* __restrict__ icnt)
{
    int e = blockIdx.x * 256 + threadIdx.x;
    if (e >= EE) return;
    int s = ei[e], d = ei[EE + e];
    t[(size_t)s * NN + d] = (u16)e;
    int slot = atomicAdd(&ocnt[s], 1);
    if (slot < MAXD) oadj[s * MAXD + slot] = e;
    slot = atomicAdd(&icnt[d], 1);
    if (slot < MAXD) iadj[d * MAXD + slot] = e;
}

__global__ __launch_bounds__(256) void rev_csr_k(const int* __restrict__ ei, const u16* __restrict__ t,
                                                 const float* __restrict__ pos,
                                                 int* __restrict__ rev,
                                                 int* __restrict__ adj, float* __restrict__ wadj,
                                                 int* __restrict__ cnt)
{
    int e = blockIdx.x * 256 + threadIdx.x;
    if (e >= EE) return;
    int s = ei[e], d = ei[EE + e];
    u16 r16 = t[(size_t)d * NN + s];
    int r = (r16 == 0xFFFFu) ? -1 : (int)r16;
    rev[e] = r;
    float dx = pos[s * 3 + 0] - pos[d * 3 + 0];
    float dy = pos[s * 3 + 1] - pos[d * 3 + 1];
    float dz = pos[s * 3 + 2] - pos[d * 3 + 2];
    float w = 1.0f / (sqrtf(dx * dx + dy * dy + dz * dz) + 1e-6f);
    int slot = atomicAdd(&cnt[s], 1);
    if (slot < MAXD) { adj[s * MAXD + slot] = d; wadj[s * MAXD + slot] = w; }
    if (r < 0) {
        slot = atomicAdd(&cnt[d], 1);
        if (slot < MAXD) { adj[d * MAXD + slot] = s; wadj[d * MAXD + slot] = w; }
    }
}

__global__ __launch_bounds__(256) void conv_all_k(
    const float* __restrict__ x, const float* __restrict__ inw, const float* __restrict__ ow,
    const float* __restrict__ etw, const float* __restrict__ unw, const float* __restrict__ uew,
    const float* __restrict__ efin, u16* __restrict__ dst)
{
    size_t i = ((size_t)blockIdx.x * 256 + threadIdx.x) * 8;
    const float* s;
    size_t off;
    if (i < 1048576)      { s = x;    off = i; }
    else if (i < 2621440) { s = inw;  off = i - 1048576; }
    else if (i < 3145728) { s = ow;   off = i - 2621440; }
    else if (i < 3670016) { s = etw;  off = i - 3145728; }
    else if (i < 4718592) { s = unw;  off = i - 3670016; }
    else if (i < 6815744) { s = uew;  off = i - 4718592; }
    else                  { s = efin; off = i - 6815744; }
    float4 a = ld4(s + off), b = ld4(s + off + 4);
    u16 o[8];
    o[0] = f2b(a.x); o[1] = f2b(a.y); o[2] = f2b(a.z); o[3] = f2b(a.w);
    o[4] = f2b(b.x); o[5] = f2b(b.y); o[6] = f2b(b.z); o[7] = f2b(b.w);
    *reinterpret_cast<int4*>(dst + i) = *reinterpret_cast<const int4*>(o);
}

// ---------------- gather-max ----------------
__global__ __launch_bounds__(256) void gather_max_k(const u16* __restrict__ te,
                                                    const int* __restrict__ oadj, const int* __restrict__ ocnt,
                                                    const int* __restrict__ iadj, const int* __restrict__ icnt,
                                                    u16* __restrict__ sums)
{
    const int i = blockIdx.x;
    const int c2 = threadIdx.x;
    float ms0 = 0.f, ms1 = 0.f, mo0 = 0.f, mo1 = 0.f;
    int no = ocnt[i]; if (no > MAXD) no = MAXD;
    for (int s = 0; s < no; ++s) {
        const int e = oadj[i * MAXD + s];
        const u32 v = *reinterpret_cast<const u32*>(te + (size_t)e * DND + c2 * 2);
        ms0 = fmaxf(ms0, b2f(v & 0xffffu));
        ms1 = fmaxf(ms1, b2f(v >> 16));
    }
    int ni = icnt[i]; if (ni > MAXD) ni = MAXD;
    for (int s = 0; s < ni; ++s) {
        const int e = iadj[i * MAXD + s];
        const u32 v = *reinterpret_cast<const u32*>(te + (size_t)e * DND + c2 * 2);
        mo0 = fmaxf(mo0, b2f(v & 0xffffu));
        mo1 = fmaxf(mo1, b2f(v >> 16));
    }
    const u32 r = (u32)f2b(ms0 + mo0) | ((u32)f2b(ms1 + mo1) << 16);
    *reinterpret_cast<u32*>(sums + (size_t)i * DND + c2 * 2) = r;
}

// ---------------- 128x128 MFMA GEMM (node GEMMs) ----------------
template <int MODE, int EPI, int WF32, int WBF16, int GY>
__global__ __launch_bounds__(256) void mgemm_k(
    const u16* __restrict__ WS, u32 a_off, u32 b_off, const float* __restrict__ bias,
    float* __restrict__ Cf, u16* __restrict__ Cb, int M, int Nc, int K,
    u32 g0_off, u32 g1_off, u32 gz_off,
    const int* __restrict__ srcv, const int* __restrict__ dstv, const int* __restrict__ revv,
    const float* __restrict__ eg, const float* __restrict__ eb)
{
    __shared__ u16 As2[2][8192];
    __shared__ u16 Bs2[2][8192];
    const int tid = threadIdx.x, lane = tid & 63, w = tid >> 6;
    const int wr = w >> 1, wc = w & 1;
    const int b = blockIdx.x;
    const int xcd = b & 7, kb = b >> 3;
    const int bm = ((kb / GY) * 8 + xcd) * 128;
    const int bn = (kb % GY) * 128;

    const int rl = lane >> 3;
    const u32 lx = (u32)(((lane & 7) ^ rl) * 8);

    u32 offA0[4], offA1[4], offB[4];
#pragma unroll
    for (int q = 0; q < 4; ++q) {
        const int ra = bm + w * 32 + q * 8 + rl;
        if (MODE == 0) {
            offA0[q] = a_off + (u32)ra * (u32)K + lx;
        } else {
            offA0[q] = g0_off + (u32)ra * 512u + lx;
            offA1[q] = g1_off + (u32)ra * 512u + lx;
        }
        offB[q] = b_off + (u32)(bn + w * 32 + q * 8 + rl) * (u32)K + lx;
    }

    const int nks = K >> 6;
    const int kq = lane >> 4, li = lane & 15;

    auto stage = [&](int t, int buf) {
        const u32 k0 = (u32)t * 64u;
        const int seg = (MODE == 0) ? 0 : (int)(k0 >> 9);
#pragma unroll
        for (int q = 0; q < 4; ++q) {
            u32 oa = (MODE == 0) ? offA0[q] : (seg == 0 ? offA0[q] : offA1[q]);
            const u32 koff = (MODE == 0) ? k0 : (k0 & 511u);
            gl_lds(WS + oa + koff, &As2[buf][(w * 32 + q * 8) * 64]);
        }
#pragma unroll
        for (int q = 0; q < 4; ++q)
            gl_lds(WS + offB[q] + k0, &Bs2[buf][(w * 32 + q * 8) * 64]);
    };

    f32x4 acc[4][4] = {};
    const int baseA = (wr * 64 + li) * 64 + ((kq ^ (li & 7)) * 8);
    const int baseB = (wc * 64 + li) * 64 + ((kq ^ (li & 7)) * 8);

    stage(0, 0);
    for (int t = 0; t < nks; ++t) {
        const int cur = t & 1;
        if (t + 1 < nks) stage(t + 1, cur ^ 1);
        if (t + 1 < nks) asm volatile("s_waitcnt vmcnt(8)" ::: "memory");
        else             asm volatile("s_waitcnt vmcnt(0)" ::: "memory");
        __builtin_amdgcn_s_barrier();
        __builtin_amdgcn_sched_barrier(0);
#pragma unroll
        for (int sub = 0; sub < 2; ++sub) {
            const int sx = sub << 5;
            bf16x8 af[4], bf[4];
#pragma unroll
            for (int m = 0; m < 4; ++m)
                af[m] = *reinterpret_cast<const bf16x8*>(&As2[cur][(baseA + m * 1024) ^ sx]);
#pragma unroll
            for (int n = 0; n < 4; ++n)
                bf[n] = *reinterpret_cast<const bf16x8*>(&Bs2[cur][(baseB + n * 1024) ^ sx]);
#pragma unroll
            for (int m = 0; m < 4; ++m)
#pragma unroll
                for (int n = 0; n < 4; ++n)
                    acc[m][n] = __builtin_amdgcn_mfma_f32_16x16x32_bf16(af[m], bf[n], acc[m][n], 0, 0, 0);
        }
        __builtin_amdgcn_s_barrier();
        __builtin_amdgcn_sched_barrier(0);
    }

    float bsv[4], scv[4], shv[4];
#pragma unroll
    for (int n = 0; n < 4; ++n) {
        const int col = bn + wc * 64 + n * 16 + li;
        bsv[n] = bias[col];
        if (EPI == 2) { scv[n] = BN_SCALE * eg[col]; shv[n] = eb[col]; }
    }
#pragma unroll
    for (int m = 0; m < 4; ++m) {
#pragma unroll
        for (int n = 0; n < 4; ++n) {
            const int col = bn + wc * 64 + n * 16 + li;
#pragma unroll
            for (int i = 0; i < 4; ++i) {
                float v = acc[m][n][i] + bsv[n];
                if (EPI == 2) v = fmaxf(fmaf(v, scv[n], shv[n]), 0.f);
                else if (EPI == 1) v = fmaxf(v, 0.f);
                const int r = bm + wr * 64 + m * 16 + (lane >> 4) * 4 + i;
                if (WF32) Cf[(size_t)r * Nc + col] = v;
                if (WBF16) Cb[(size_t)r * Nc + col] = f2b(v);
            }
        }
    }
}

// ---------------- 256x256 MFMA GEMM (edge GEMMs), deep-pipeline 4-phase schedule ----------
// 8 waves, BK=64, 128 KB LDS 2-deep dbuf. Quadrant-phased MFMA (P1..P4 per K-tile) creates
// sub-buffer lifetimes: Aalpha (rows 0-63,128-191) dead after P2, Bgamma (cols n0-1) after P3.
// Stages: P1->A(t+1,beta) P2->B(t+1,delta) P3->A(t+2,alpha) P4->B(t+2,gamma), so loads get
// 4-6 phases of flight. Counted waits: end-P1 vmcnt(6), end-P4 vmcnt(8) (tail-adjusted),
// never drained mid-loop. Per phase: ds_read 12xb128 | stage | barrier | lgkmcnt(0) |
// setprio(1) 16 MFMA setprio(0) | [vmcnt] | barrier.   (T2+T3+T4+T5 combo, m201 structure)
template <int MODE, int EPI, int WF32, int WBF16>
__global__ __launch_bounds__(512, 2) void mgemm256_k(
    const u16* __restrict__ WS, u32 a_off, u32 b_off, const float* __restrict__ bias,
    float* __restrict__ Cf, u16* __restrict__ Cb, int M, int Nc, int K,
    u32 g0_off, u32 g1_off, u32 gz_off,
    const int* __restrict__ srcv, const int* __restrict__ dstv, const int* __restrict__ revv,
    const float* __restrict__ eg, const float* __restrict__ eb)
{
    __shared__ u16 SB[65536];   // A: [0..32K) 2 x 16K, B: [32K..64K) 2 x 16K
    const int tid = threadIdx.x, lane = tid & 63, w = tid >> 6;
    const int wr = w >> 2, wc = w & 3;
    const int b = blockIdx.x;
    const int bm = ((b & 7) + 8 * (b >> 4)) * 256;
    const int bn = ((b >> 3) & 1) * 256;

    const int rl = lane >> 3;
    const u32 lx = (u32)(((lane & 7) ^ rl) * 8);

    // LDS row bases per (half h, q): A half0=rows{0-63,128-191}, half1=+64; B half0=cols n0-1 groups
    int arb[4], brb[4];
#pragma unroll
    for (int h = 0; h < 2; ++h)
#pragma unroll
        for (int q = 0; q < 2; ++q) {
            arb[h * 2 + q] = (w < 4 ? w * 16 : 128 + (w - 4) * 16) + h * 64 + q * 8;
            brb[h * 2 + q] = (w >> 1) * 64 + (w & 1) * 16 + h * 32 + q * 8;
        }

    u32 offA0[4], offA1[4], offA2[4], offA3[4], offB[4];
#pragma unroll
    for (int i = 0; i < 4; ++i) {
        const int ra = bm + arb[i] + rl;
        if (MODE == 0) {
            offA0[i] = a_off + (u32)ra * (u32)K + lx;
        } else {
            offA0[i] = g0_off + (u32)srcv[ra] * 512u + lx;
            offA1[i] = g1_off + (u32)ra * 512u + lx;
            const int rv = revv[ra];
            offA2[i] = (rv >= 0 ? g1_off + (u32)rv * 512u : gz_off) + lx;
            offA3[i] = g0_off + (u32)dstv[ra] * 512u + lx;
        }
        offB[i] = b_off + (u32)(bn + brb[i] + rl) * (u32)K + lx;
    }

    const int nks = K >> 6;   // requires nks >= 2
    const int kq = lane >> 4, li = lane & 15;

    auto stageA = [&](int t, int h) {
        const u32 k0 = (u32)t * 64u;
        const int par = t & 1;
        const int seg = (MODE == 0) ? 0 : (int)(k0 >> 9);
        const u32 koff = (MODE == 0) ? k0 : (k0 & 511u);
#pragma unroll
        for (int q = 0; q < 2; ++q) {
            const int i = h * 2 + q;
            u32 oa;
            if (MODE == 0) oa = offA0[i];
            else           oa = (seg == 0 ? offA0[i] : seg == 1 ? offA1[i] : seg == 2 ? offA2[i] : offA3[i]);
            gl_lds(WS + oa + koff, &SB[par * 16384 + arb[i] * 64]);
        }
    };
    auto stageB = [&](int t, int h) {
        const u32 k0 = (u32)t * 64u;
        const int par = t & 1;
#pragma unroll
        for (int q = 0; q < 2; ++q) {
            const int i = h * 2 + q;
            gl_lds(WS + offB[i] + k0, &SB[32768 + par * 16384 + brb[i] * 64]);
        }
    };

    f32x4 acc[8][4] = {};
    const u32 swz = (u32)((kq ^ (li & 7)) * 8);

    // prologue: Aa(0) Bg(0) Ab(0) Bd(0) Aa(1) Bg(1); force tile-0 alpha/gamma (4 oldest loads)
    stageA(0, 0); stageB(0, 0); stageA(0, 1); stageB(0, 1);
    if (nks > 1) { stageA(1, 0); stageB(1, 0); }
    asm volatile("s_waitcnt vmcnt(8)" ::: "memory");
    __builtin_amdgcn_s_barrier();

    for (int t = 0; t < nks; ++t) {
        const int pA = (t & 1) * 16384, pB = 32768 + (t & 1) * 16384;
#pragma unroll
        for (int ph = 0; ph < 4; ++ph) {
            const int mq = ph >> 1, nq = ph & 1;
            bf16x8 af[2][4], bf[2][2];
#pragma unroll
            for (int ks = 0; ks < 2; ++ks) {
#pragma unroll
                for (int mi = 0; mi < 4; ++mi)
                    af[ks][mi] = *reinterpret_cast<const bf16x8*>(
                        &SB[pA + (wr * 128 + (mq * 4 + mi) * 16 + li) * 64 + (swz ^ (ks << 5))]);
#pragma unroll
                for (int ni = 0; ni < 2; ++ni)
                    bf[ks][ni] = *reinterpret_cast<const bf16x8*>(
                        &SB[pB + (wc * 64 + (nq * 2 + ni) * 16 + li) * 64 + (swz ^ (ks << 5))]);
            }
            if (ph == 0)      { if (t + 1 < nks) stageA(t + 1, 1); }
            else if (ph == 1) { if (t + 1 < nks) stageB(t + 1, 1); }
            else if (ph == 2) { if (t + 2 < nks) stageA(t + 2, 0); }
            else              { if (t + 2 < nks) stageB(t + 2, 0); }
            __builtin_amdgcn_s_barrier();
            asm volatile("s_waitcnt lgkmcnt(0)" ::: "memory");
            __builtin_amdgcn_sched_barrier(0);
            __builtin_amdgcn_s_setprio(1);
#pragma unroll
            for (int ks = 0; ks < 2; ++ks)
#pragma unroll
                for (int mi = 0; mi < 4; ++mi)
#pragma unroll
                    for (int ni = 0; ni < 2; ++ni)
                        acc[mq * 4 + mi][nq * 2 + ni] = __builtin_amdgcn_mfma_f32_16x16x32_bf16(
                            af[ks][mi], bf[ks][ni], acc[mq * 4 + mi][nq * 2 + ni], 0, 0, 0);
            __builtin_amdgcn_s_setprio(0);
            __builtin_amdgcn_sched_barrier(0);
            if (ph == 0) {
                if (t + 1 < nks) asm volatile("s_waitcnt vmcnt(6)" ::: "memory");
                else             asm volatile("s_waitcnt vmcnt(0)" ::: "memory");
            } else if (ph == 3) {
                if (t + 2 < nks) asm volatile("s_waitcnt vmcnt(8)" ::: "memory");
                else             asm volatile("s_waitcnt vmcnt(4)" ::: "memory");
            }
            __builtin_amdgcn_s_barrier();
        }
    }

    float bsv[4], scv[4], shv[4];
#pragma unroll
    for (int n = 0; n < 4; ++n) {
        const int col = bn + wc * 64 + n * 16 + li;
        bsv[n] = bias[col];
        if (EPI == 2) { scv[n] = BN_SCALE * eg[col]; shv[n] = eb[col]; }
    }
#pragma unroll
    for (int m = 0; m < 8; ++m) {
#pragma unroll
        for (int n = 0; n < 4; ++n) {
            const int col = bn + wc * 64 + n * 16 + li;
#pragma unroll
            for (int i = 0; i < 4; ++i) {
                float v = acc[m][n][i] + bsv[n];
                if (EPI == 2) v = fmaxf(fmaf(v, scv[n], shv[n]), 0.f);
                else if (EPI == 1) v = fmaxf(v, 0.f);
                const int r = bm + wr * 128 + m * 16 + (lane >> 4) * 4 + i;
                if (WF32) Cf[(size_t)r * Nc + col] = v;
                if (WBF16) Cb[(size_t)r * Nc + col] = f2b(v);
            }
        }
    }
}

// ---------------- sparse attention (bf16 qkv): 1 wave per (node, head) ----------------
__global__ __launch_bounds__(256) void attn_sp_k(const u16* __restrict__ qkvb,
                                                 const int* __restrict__ adj,
                                                 const float* __restrict__ wadj,
                                                 const int* __restrict__ cnt,
                                                 u16* __restrict__ ctxb)
{
    const int i = blockIdx.x;
    const int wv = threadIdx.x >> 6, lane = threadIdx.x & 63;
    const int h = blockIdx.y * 4 + wv;
    __shared__ float qs[4][64];
    qs[wv][lane] = b2f((u32)qkvb[(size_t)i * 1536 + h * HD + lane]) * 0.125f;
    __syncthreads();
    int deg = cnt[i];
    if (deg > MAXD) deg = MAXD;
    float m = -3.0e38f, lsum = 0.f, c = 0.f;
    for (int base = 0; base < deg; base += 64) {
        int nn_ = deg - base; if (nn_ > 64) nn_ = 64;
        int j = 0;
        float s = NEGF;
        if (lane < nn_) {
            j = adj[i * MAXD + base + lane];
            const float wgt = wadj[i * MAXD + base + lane];
            const u16* kr = qkvb + (size_t)j * 1536 + DND + h * HD;
            float accd = 0.f;
#pragma unroll
            for (int cq = 0; cq < 4; ++cq) {
                uint4 kv = *reinterpret_cast<const uint4*>(kr + cq * 16);
                const float* qp = &qs[wv][cq * 16];
                accd = fmaf(qp[0],  b2f(kv.x & 0xffffu), accd);
                accd = fmaf(qp[1],  b2f(kv.x >> 16), accd);
                accd = fmaf(qp[2],  b2f(kv.y & 0xffffu), accd);
                accd = fmaf(qp[3],  b2f(kv.y >> 16), accd);
                accd = fmaf(qp[4],  b2f(kv.z & 0xffffu), accd);
                accd = fmaf(qp[5],  b2f(kv.z >> 16), accd);
                accd = fmaf(qp[6],  b2f(kv.w & 0xffffu), accd);
                accd = fmaf(qp[7],  b2f(kv.w >> 16), accd);
                uint4 kv2 = *reinterpret_cast<const uint4*>(kr + cq * 16 + 8);
                accd = fmaf(qp[8],  b2f(kv2.x & 0xffffu), accd);
                accd = fmaf(qp[9],  b2f(kv2.x >> 16), accd);
                accd = fmaf(qp[10], b2f(kv2.y & 0xffffu), accd);
                accd = fmaf(qp[11], b2f(kv2.y >> 16), accd);
                accd = fmaf(qp[12], b2f(kv2.z & 0xffffu), accd);
                accd = fmaf(qp[13], b2f(kv2.z >> 16), accd);
                accd = fmaf(qp[14], b2f(kv2.w & 0xffffu), accd);
                accd = fmaf(qp[15], b2f(kv2.w >> 16), accd);
            }
            s = accd + wgt;
        }
        float mloc = s;
#pragma unroll
        for (int o = 1; o < 64; o <<= 1) mloc = fmaxf(mloc, __shfl_xor(mloc, o, 64));
        const float mnew = fmaxf(m, mloc);
        const float alpha = __expf(m - mnew);
        const float p = (lane < nn_) ? __expf(s - mnew) : 0.f;
        float ps = p;
#pragma unroll
        for (int o = 1; o < 64; o <<= 1) ps += __shfl_xor(ps, o, 64);
        lsum = lsum * alpha + ps;
        c *= alpha;
        for (int l = 0; l < nn_; ++l) {
            const float pj = __shfl(p, l, 64);
            const int jj = __shfl(j, l, 64);
            c = fmaf(pj, b2f((u32)qkvb[(size_t)jj * 1536 + 2 * DND + h * HD + lane]), c);
        }
        m = mnew;
    }
    ctxb[(size_t)i * DND + h * HD + lane] = f2b(c / lsum);
}

// ---------------- host orchestration ----------------
extern "C" void kernel_launch(void* const* d_in, const int* in_sizes, int n_in,
                              void* d_out, int out_size, void* d_ws, size_t ws_size,
                              hipStream_t stream)
{
    const float* x    = (const float*)d_in[0];
    const float* efin = (const float*)d_in[1];
    const float* pos  = (const float*)d_in[2];
    const float* inw  = (const float*)d_in[3];
    const float* inb  = (const float*)d_in[4];
    const float* ow   = (const float*)d_in[5];
    const float* ob   = (const float*)d_in[6];
    const float* etw  = (const float*)d_in[7];
    const float* etb  = (const float*)d_in[8];
    const float* etg  = (const float*)d_in[9];
    const float* etbb = (const float*)d_in[10];
    const float* unw  = (const float*)d_in[11];
    const float* unb  = (const float*)d_in[12];
    const float* uew  = (const float*)d_in[13];
    const float* ueb  = (const float*)d_in[14];
    const int*   ei   = (const int*)d_in[15];

    // workspace layout (offsets in floats) -- R13/R15 layout
    float* W = (float*)d_ws;
    u16*   qkvb  = (u16*)W;                          // union: qkvb bf16 / te bf16 (33.5MB)
    u16*   te    = (u16*)W;
    int*   rev   = (int*)(W + 8388608);
    u16*   zero  = (u16*)(W + 8421376);              // 1024 u16
    int*   adj   = (int*)(W + 8421888);
    float* wadj  = W + 8684032;
    int*   cnt   = (int*)(W + 8946176);
    int*   oadj  = (int*)(W + 8948224);
    int*   ocnt  = (int*)(W + 9210368);
    int*   iadj  = (int*)(W + 9212416);
    int*   icnt  = (int*)(W + 9474560);
    u16*   ctxb  = (u16*)(W + 9476608);
    u16*   xupdb = (u16*)(W + 10000896);
    u16*   sums  = (u16*)(W + 10525184);
    u16*   nfb   = (u16*)(W + 11049472);             // contiguous: nfb | wbf | efbA
    u16*   wbf   = (u16*)(W + 11573760);
    u16*   efbA  = (u16*)(W + 14457344);
    u16*   efbB  = (u16*)(W + 22845952);
    u16*   table = (u16*)efbA;                       // alias: setup-only
    // total: 31,234,560 floats = 124.9 MB

    u16* inwb = wbf;
    u16* owb  = wbf + 1572864;
    u16* etwb = wbf + 2097152;
    u16* unwb = wbf + 2621440;
    u16* uewb = wbf + 3670016;

    float* out_nf = (float*)d_out;
    float* out_ef = out_nf + (size_t)NN * DND;

    const int* srcv = ei;
    const int* dstv = ei + EE;

    const u16* WSu = (const u16*)d_ws;
    auto uoff = [&](const void* p) { return (u32)((const u16*)p - WSu); };

    // consolidated setup: 4 dispatches
    setup_init_k<<<NN * NN / 512, 256, 0, stream>>>((u32*)table, adj, wadj, cnt, ocnt, icnt, zero);
    fill_scatter_k<<<EE / 256, 256, 0, stream>>>(ei, table, oadj, ocnt, iadj, icnt);
    rev_csr_k<<<EE / 256, 256, 0, stream>>>(ei, table, pos, rev, adj, wadj, cnt);
    conv_all_k<<<11520, 256, 0, stream>>>(x, inw, ow, etw, unw, uew, efin, nfb);

    for (int l = 0; l < 2; ++l) {
        const u16* efb_cur = l ? efbB : efbA;
        const u16* inwb_l = inwb + (size_t)l * 786432;
        const u16* owb_l  = owb  + (size_t)l * 262144;
        const u16* etwb_l = etwb + (size_t)l * 262144;
        const u16* unwb_l = unwb + (size_t)l * 524288;
        const u16* uewb_l = uewb + (size_t)l * 1048576;
        const float* inb_l  = inb  + (size_t)l * 1536;
        const float* ob_l   = ob   + (size_t)l * 512;
        const float* etb_l  = etb  + (size_t)l * 512;
        const float* etg_l  = etg  + (size_t)l * 512;
        const float* etbb_l = etbb + (size_t)l * 512;
        const float* unb_l  = unb  + (size_t)l * 512;
        const float* ueb_l  = ueb  + (size_t)l * 512;

        // qkv = nf @ inw^T + inb   (bf16 out)
        mgemm_k<0, 0, 0, 1, 12><<<192, 256, 0, stream>>>(
            WSu, uoff(nfb), uoff(inwb_l), inb_l, nullptr, qkvb, NN, 1536, DND,
            0, 0, 0, nullptr, nullptr, nullptr, nullptr, nullptr);

        // sparse masked MHSA -> ctx (bf16)
        attn_sp_k<<<dim3(NN, 2), 256, 0, stream>>>(qkvb, adj, wadj, cnt, ctxb);

        // x_upd = ctx @ ow^T + ob  (bf16)
        mgemm_k<0, 0, 0, 1, 4><<<64, 256, 0, stream>>>(
            WSu, uoff(ctxb), uoff(owb_l), ob_l, nullptr, xupdb, NN, DND, DND,
            0, 0, 0, nullptr, nullptr, nullptr, nullptr, nullptr);

        // te = relu(BN(ef @ etw^T + etb))  (bf16, deep-pipeline 256^2; overwrites dead qkvb)
        mgemm256_k<0, 2, 0, 1><<<256, 512, 0, stream>>>(
            WSu, uoff(efb_cur), uoff(etwb_l), etb_l, nullptr, te, EE, DND, DND,
            0, 0, 0, nullptr, nullptr, nullptr, etg_l, etbb_l);

        // sums = bf16(max_out te + max_in te)
        gather_max_k<<<NN, 256, 0, stream>>>(te, oadj, ocnt, iadj, icnt, sums);

        // ef_next = (relu?)([nf[src], ef, ef[rev], nf[dst]] @ uew^T + ueb)
        if (l == 0)
            mgemm256_k<1, 1, 0, 1><<<256, 512, 0, stream>>>(
                WSu, 0, uoff(uewb_l), ueb_l, nullptr, efbB, EE, DND, 2048,
                uoff(nfb), uoff(efb_cur), uoff(zero), srcv, dstv, rev, nullptr, nullptr);
        else
            mgemm256_k<1, 0, 1, 0><<<256, 512, 0, stream>>>(
                WSu, 0, uoff(uewb_l), ueb_l, out_ef, nullptr, EE, DND, 2048,
                uoff(nfb), uoff(efb_cur), uoff(zero), srcv, dstv, rev, nullptr, nullptr);

        // nf_next = (relu?)([x_upd, subj+obj] @ unw^T + unb)
        if (l == 0)
            mgemm_k<2, 1, 0, 1, 4><<<64, 256, 0, stream>>>(
                WSu, 0, uoff(unwb_l), unb_l, nullptr, nfb, NN, DND, 1024,
                uoff(xupdb), uoff(sums), 0, nullptr, nullptr, nullptr, nullptr, nullptr);
        else
            mgemm_k<2, 0, 1, 0, 4><<<64, 256, 0, stream>>>(
                WSu, 0, uoff(unwb_l), unb_l, out_nf, nullptr, NN, DND, 1024,
                uoff(xupdb), uoff(sums), 0, nullptr, nullptr, nullptr, nullptr, nullptr);
    }
}

// Round 17
// 429.623 us; speedup vs baseline: 1.0831x; 1.0831x over previous
//
#include <hip/hip_runtime.h>
#include <hip/hip_bf16.h>

#define NN 2048
#define EE 32768
#define DND 512
#define NH 8
#define HD 64
#define MAXD 128
#define NEGF (-1e30f)
#define BN_SCALE 0.9999950000374997f  // 1/sqrt(1+1e-5)

typedef __attribute__((ext_vector_type(8))) short bf16x8;
typedef __attribute__((ext_vector_type(4))) float f32x4;
typedef unsigned short u16;
typedef unsigned int u32;

static __device__ __forceinline__ float4 ld4(const float* p) {
    return *reinterpret_cast<const float4*>(p);
}
static __device__ __forceinline__ u16 f2b(float f) {
    __hip_bfloat16 h = __float2bfloat16(f);
    return *reinterpret_cast<u16*>(&h);
}
static __device__ __forceinline__ float b2f(u32 bits) {
    return __uint_as_float(bits << 16);
}
static __device__ __forceinline__ void gl_lds(const u16* g, u16* l) {
    __builtin_amdgcn_global_load_lds((const __attribute__((address_space(1))) void*)g,
                                     (__attribute__((address_space(3))) void*)l, 16, 0, 0);
}

// ---------------- consolidated setup kernels ----------------

// grid NN*NN/512: table=0xFFFF everywhere (u32 stores, 2 u16 entries/thread);
// low ids also init CSR counters + zero buf
__global__ __launch_bounds__(256) void setup_init_k(u32* __restrict__ t2,
                                                    int* __restrict__ adj, float* __restrict__ wadj,
                                                    int* __restrict__ cnt,
                                                    int* __restrict__ ocnt, int* __restrict__ icnt,
                                                    u16* __restrict__ zero)
{
    int i = blockIdx.x * 256 + threadIdx.x;
    t2[i] = 0xFFFFFFFFu;
    if (i < NN) {
        cnt[i] = 1; adj[i * MAXD] = i; wadj[i * MAXD] = 1.0f;
        ocnt[i] = 0; icnt[i] = 0;
    }
    if (i < 1024) zero[i] = 0;
}

// grid EE/256: fill edge table (u16) + out/in edge-id CSRs
__global__ __launch_bounds__(256) void fill_scatter_k(const int* __restrict__ ei, u16* __restrict__ t,
                                                      int* __restrict__ oadj, int* __restrict__ ocnt,
                                                      int* __restrict__ iadj, int* __restrict__ icnt)
{
    int e = blockIdx.x * 256 + threadIdx.x;
    if (e >= EE) return;
    int s = ei[e], d = ei[EE + e];
    t[(size_t)s * NN + d] = (u16)e;
    int slot = atomicAdd(&ocnt[s], 1);
    if (slot < MAXD) oadj[s * MAXD + slot] = e;
    slot = atomicAdd(&icnt[d], 1);
    if (slot < MAXD) iadj[d * MAXD + slot] = e;
}

// grid EE/256: rev[e] from table + attention CSR fill (slot0=self preset in init)
__global__ __launch_bounds__(256) void rev_csr_k(const int* __restrict__ ei, const u16* __restrict__ t,
                                                 const float* __restrict__ pos,
                                                 int* __restrict__ rev,
                                                 int* __restrict__ adj, float* __restrict__ wadj,
                                                 int* __restrict__ cnt)
{
    int e = blockIdx.x * 256 + threadIdx.x;
    if (e >= EE) return;
    int s = ei[e], d = ei[EE + e];
    u16 r16 = t[(size_t)d * NN + s];
    int r = (r16 == 0xFFFFu) ? -1 : (int)r16;
    rev[e] = r;
    float dx = pos[s * 3 + 0] - pos[d * 3 + 0];
    float dy = pos[s * 3 + 1] - pos[d * 3 + 1];
    float dz = pos[s * 3 + 2] - pos[d * 3 + 2];
    float w = 1.0f / (sqrtf(dx * dx + dy * dy + dz * dz) + 1e-6f);
    int slot = atomicAdd(&cnt[s], 1);
    if (slot < MAXD) { adj[s * MAXD + slot] = d; wadj[s * MAXD + slot] = w; }
    if (r < 0) {
        slot = atomicAdd(&cnt[d], 1);
        if (slot < MAXD) { adj[d * MAXD + slot] = s; wadj[d * MAXD + slot] = w; }
    }
}

// single conv pass: [x | inw | ow | etw | unw | uew | efin] -> contiguous [nfb|wbf|efbA]
__global__ __launch_bounds__(256) void conv_all_k(
    const float* __restrict__ x, const float* __restrict__ inw, const float* __restrict__ ow,
    const float* __restrict__ etw, const float* __restrict__ unw, const float* __restrict__ uew,
    const float* __restrict__ efin, u16* __restrict__ dst)
{
    size_t i = ((size_t)blockIdx.x * 256 + threadIdx.x) * 8;
    const float* s;
    size_t off;
    if (i < 1048576)      { s = x;    off = i; }
    else if (i < 2621440) { s = inw;  off = i - 1048576; }
    else if (i < 3145728) { s = ow;   off = i - 2621440; }
    else if (i < 3670016) { s = etw;  off = i - 3145728; }
    else if (i < 4718592) { s = unw;  off = i - 3670016; }
    else if (i < 6815744) { s = uew;  off = i - 4718592; }
    else                  { s = efin; off = i - 6815744; }
    float4 a = ld4(s + off), b = ld4(s + off + 4);
    u16 o[8];
    o[0] = f2b(a.x); o[1] = f2b(a.y); o[2] = f2b(a.z); o[3] = f2b(a.w);
    o[4] = f2b(b.x); o[5] = f2b(b.y); o[6] = f2b(b.z); o[7] = f2b(b.w);
    *reinterpret_cast<int4*>(dst + i) = *reinterpret_cast<const int4*>(o);
}

// ---------------- gather-max: sums[i] = bf16(max_out te[e] + max_in te[e]) ----------------
__global__ __launch_bounds__(256) void gather_max_k(const u16* __restrict__ te,
                                                    const int* __restrict__ oadj, const int* __restrict__ ocnt,
                                                    const int* __restrict__ iadj, const int* __restrict__ icnt,
                                                    u16* __restrict__ sums)
{
    const int i = blockIdx.x;
    const int c2 = threadIdx.x;  // 0..255
    float ms0 = 0.f, ms1 = 0.f, mo0 = 0.f, mo1 = 0.f;
    int no = ocnt[i]; if (no > MAXD) no = MAXD;
    for (int s = 0; s < no; ++s) {
        const int e = oadj[i * MAXD + s];
        const u32 v = *reinterpret_cast<const u32*>(te + (size_t)e * DND + c2 * 2);
        ms0 = fmaxf(ms0, b2f(v & 0xffffu));
        ms1 = fmaxf(ms1, b2f(v >> 16));
    }
    int ni = icnt[i]; if (ni > MAXD) ni = MAXD;
    for (int s = 0; s < ni; ++s) {
        const int e = iadj[i * MAXD + s];
        const u32 v = *reinterpret_cast<const u32*>(te + (size_t)e * DND + c2 * 2);
        mo0 = fmaxf(mo0, b2f(v & 0xffffu));
        mo1 = fmaxf(mo1, b2f(v >> 16));
    }
    const u32 r = (u32)f2b(ms0 + mo0) | ((u32)f2b(ms1 + mo1) << 16);
    *reinterpret_cast<u32*>(sums + (size_t)i * DND + c2 * 2) = r;
}

// ---------------- 128x128 MFMA GEMM (node GEMMs): C = epi(A @ B^T + bias) ----------------
// MODE 0: A plain row-major at a_off   MODE 2: A = [g0, g1] (K=1024)
// EPI 0: +bias  EPI 1: relu  EPI 2: relu(BN)
template <int MODE, int EPI, int WF32, int WBF16, int GY>
__global__ __launch_bounds__(256) void mgemm_k(
    const u16* __restrict__ WS, u32 a_off, u32 b_off, const float* __restrict__ bias,
    float* __restrict__ Cf, u16* __restrict__ Cb, int M, int Nc, int K,
    u32 g0_off, u32 g1_off, u32 gz_off,
    const int* __restrict__ srcv, const int* __restrict__ dstv, const int* __restrict__ revv,
    const float* __restrict__ eg, const float* __restrict__ eb)
{
    __shared__ u16 As2[2][8192];
    __shared__ u16 Bs2[2][8192];
    const int tid = threadIdx.x, lane = tid & 63, w = tid >> 6;
    const int wr = w >> 1, wc = w & 1;
    const int b = blockIdx.x;
    const int xcd = b & 7, kb = b >> 3;
    const int bm = ((kb / GY) * 8 + xcd) * 128;
    const int bn = (kb % GY) * 128;

    const int rl = lane >> 3;
    const u32 lx = (u32)(((lane & 7) ^ rl) * 8);

    u32 offA0[4], offA1[4], offB[4];
#pragma unroll
    for (int q = 0; q < 4; ++q) {
        const int ra = bm + w * 32 + q * 8 + rl;
        if (MODE == 0) {
            offA0[q] = a_off + (u32)ra * (u32)K + lx;
        } else {
            offA0[q] = g0_off + (u32)ra * 512u + lx;
            offA1[q] = g1_off + (u32)ra * 512u + lx;
        }
        offB[q] = b_off + (u32)(bn + w * 32 + q * 8 + rl) * (u32)K + lx;
    }

    const int nks = K >> 6;
    const int kq = lane >> 4, li = lane & 15;

    auto stage = [&](int t, int buf) {
        const u32 k0 = (u32)t * 64u;
        const int seg = (MODE == 0) ? 0 : (int)(k0 >> 9);
#pragma unroll
        for (int q = 0; q < 4; ++q) {
            u32 oa = (MODE == 0) ? offA0[q] : (seg == 0 ? offA0[q] : offA1[q]);
            const u32 koff = (MODE == 0) ? k0 : (k0 & 511u);
            gl_lds(WS + oa + koff, &As2[buf][(w * 32 + q * 8) * 64]);
        }
#pragma unroll
        for (int q = 0; q < 4; ++q)
            gl_lds(WS + offB[q] + k0, &Bs2[buf][(w * 32 + q * 8) * 64]);
    };

    f32x4 acc[4][4] = {};
    const int baseA = (wr * 64 + li) * 64 + ((kq ^ (li & 7)) * 8);
    const int baseB = (wc * 64 + li) * 64 + ((kq ^ (li & 7)) * 8);

    stage(0, 0);
    for (int t = 0; t < nks; ++t) {
        const int cur = t & 1;
        if (t + 1 < nks) stage(t + 1, cur ^ 1);
        if (t + 1 < nks) asm volatile("s_waitcnt vmcnt(8)" ::: "memory");
        else             asm volatile("s_waitcnt vmcnt(0)" ::: "memory");
        __builtin_amdgcn_s_barrier();
        __builtin_amdgcn_sched_barrier(0);
#pragma unroll
        for (int sub = 0; sub < 2; ++sub) {
            const int sx = sub << 5;
            bf16x8 af[4], bf[4];
#pragma unroll
            for (int m = 0; m < 4; ++m)
                af[m] = *reinterpret_cast<const bf16x8*>(&As2[cur][(baseA + m * 1024) ^ sx]);
#pragma unroll
            for (int n = 0; n < 4; ++n)
                bf[n] = *reinterpret_cast<const bf16x8*>(&Bs2[cur][(baseB + n * 1024) ^ sx]);
#pragma unroll
            for (int m = 0; m < 4; ++m)
#pragma unroll
                for (int n = 0; n < 4; ++n)
                    acc[m][n] = __builtin_amdgcn_mfma_f32_16x16x32_bf16(af[m], bf[n], acc[m][n], 0, 0, 0);
        }
        __builtin_amdgcn_s_barrier();
        __builtin_amdgcn_sched_barrier(0);
    }

    float bsv[4], scv[4], shv[4];
#pragma unroll
    for (int n = 0; n < 4; ++n) {
        const int col = bn + wc * 64 + n * 16 + li;
        bsv[n] = bias[col];
        if (EPI == 2) { scv[n] = BN_SCALE * eg[col]; shv[n] = eb[col]; }
    }
#pragma unroll
    for (int m = 0; m < 4; ++m) {
#pragma unroll
        for (int n = 0; n < 4; ++n) {
            const int col = bn + wc * 64 + n * 16 + li;
#pragma unroll
            for (int i = 0; i < 4; ++i) {
                float v = acc[m][n][i] + bsv[n];
                if (EPI == 2) v = fmaxf(fmaf(v, scv[n], shv[n]), 0.f);
                else if (EPI == 1) v = fmaxf(v, 0.f);
                const int r = bm + wr * 64 + m * 16 + (lane >> 4) * 4 + i;
                if (WF32) Cf[(size_t)r * Nc + col] = v;
                if (WBF16) Cb[(size_t)r * Nc + col] = f2b(v);
            }
        }
    }
}

// ---------------- 256x256 MFMA GEMM (edge GEMMs), R11 schedule ----------------
template <int MODE, int EPI, int WF32, int WBF16>
__global__ __launch_bounds__(512, 2) void mgemm256_k(
    const u16* __restrict__ WS, u32 a_off, u32 b_off, const float* __restrict__ bias,
    float* __restrict__ Cf, u16* __restrict__ Cb, int M, int Nc, int K,
    u32 g0_off, u32 g1_off, u32 gz_off,
    const int* __restrict__ srcv, const int* __restrict__ dstv, const int* __restrict__ revv,
    const float* __restrict__ eg, const float* __restrict__ eb)
{
    __shared__ u16 SB[65536];
    const int tid = threadIdx.x, lane = tid & 63, w = tid >> 6;
    const int wr = w >> 2, wc = w & 3;
    const int b = blockIdx.x;
    const int bm = ((b & 7) + 8 * (b >> 4)) * 256;
    const int bn = ((b >> 3) & 1) * 256;

    const int rl = lane >> 3;
    const u32 lx = (u32)(((lane & 7) ^ rl) * 8);

    u32 offA0[4], offA1[4], offA2[4], offA3[4], offB[4];
#pragma unroll
    for (int q = 0; q < 4; ++q) {
        const int ra = bm + w * 32 + q * 8 + rl;
        if (MODE == 0) {
            offA0[q] = a_off + (u32)ra * (u32)K + lx;
        } else {
            offA0[q] = g0_off + (u32)srcv[ra] * 512u + lx;
            offA1[q] = g1_off + (u32)ra * 512u + lx;
            const int rv = revv[ra];
            offA2[q] = (rv >= 0 ? g1_off + (u32)rv * 512u : gz_off) + lx;
            offA3[q] = g0_off + (u32)dstv[ra] * 512u + lx;
        }
        offB[q] = b_off + (u32)(bn + w * 32 + q * 8 + rl) * (u32)K + lx;
    }

    const int nks = K >> 6;
    const int kq = lane >> 4, li = lane & 15;

    auto stageA2 = [&](int t, int buf, int q0) {
        const u32 k0 = (u32)t * 64u;
        const int seg = (MODE == 0) ? 0 : (int)(k0 >> 9);
        const u32 koff = (MODE == 0) ? k0 : (k0 & 511u);
#pragma unroll
        for (int q = q0; q < q0 + 2; ++q) {
            u32 oa;
            if (MODE == 0) oa = offA0[q];
            else           oa = (seg == 0 ? offA0[q] : seg == 1 ? offA1[q] : seg == 2 ? offA2[q] : offA3[q]);
            gl_lds(WS + oa + koff, &SB[buf * 16384 + (w * 32 + q * 8) * 64]);
        }
    };
    auto stageB2 = [&](int t, int buf, int q0) {
        const u32 k0 = (u32)t * 64u;
#pragma unroll
        for (int q = q0; q < q0 + 2; ++q)
            gl_lds(WS + offB[q] + k0, &SB[32768 + buf * 16384 + (w * 32 + q * 8) * 64]);
    };

    f32x4 acc[8][4] = {};
    const int baseA = (wr * 128 + li) * 64 + ((kq ^ (li & 7)) * 8);
    const int baseB = (wc * 64 + li) * 64 + ((kq ^ (li & 7)) * 8);

    stageA2(0, 0, 0); stageA2(0, 0, 2); stageB2(0, 0, 0); stageB2(0, 0, 2);
    for (int t = 0; t < nks; ++t) {
        const int cur = t & 1;
        const bool pf = (t + 1 < nks);
        if (pf) {
            stageA2(t + 1, cur ^ 1, 0);
            asm volatile("s_waitcnt vmcnt(2)" ::: "memory");
        } else {
            asm volatile("s_waitcnt vmcnt(0)" ::: "memory");
        }
        __builtin_amdgcn_s_barrier();
        __builtin_amdgcn_sched_barrier(0);
#pragma unroll
        for (int sub = 0; sub < 2; ++sub) {
            const int sx = sub << 5;
            bf16x8 bf[4];
#pragma unroll
            for (int n = 0; n < 4; ++n)
                bf[n] = *reinterpret_cast<const bf16x8*>(&SB[(32768 + cur * 16384 + baseB + n * 1024) ^ sx]);
#pragma unroll
            for (int mh = 0; mh < 2; ++mh) {
                if (pf) {
                    if (sub == 0 && mh == 0)      stageA2(t + 1, cur ^ 1, 2);
                    else if (sub == 0 && mh == 1) stageB2(t + 1, cur ^ 1, 0);
                    else if (sub == 1 && mh == 0) stageB2(t + 1, cur ^ 1, 2);
                }
                bf16x8 af[4];
#pragma unroll
                for (int m = 0; m < 4; ++m)
                    af[m] = *reinterpret_cast<const bf16x8*>(&SB[(cur * 16384 + baseA + (mh * 4 + m) * 1024) ^ sx]);
                __builtin_amdgcn_sched_barrier(0);
                __builtin_amdgcn_s_setprio(1);
#pragma unroll
                for (int m = 0; m < 4; ++m)
#pragma unroll
                    for (int n = 0; n < 4; ++n)
                        acc[mh * 4 + m][n] =
                            __builtin_amdgcn_mfma_f32_16x16x32_bf16(af[m], bf[n], acc[mh * 4 + m][n], 0, 0, 0);
                __builtin_amdgcn_s_setprio(0);
                __builtin_amdgcn_sched_barrier(0);
            }
        }
        __builtin_amdgcn_s_barrier();
        __builtin_amdgcn_sched_barrier(0);
    }

    float bsv[4], scv[4], shv[4];
#pragma unroll
    for (int n = 0; n < 4; ++n) {
        const int col = bn + wc * 64 + n * 16 + li;
        bsv[n] = bias[col];
        if (EPI == 2) { scv[n] = BN_SCALE * eg[col]; shv[n] = eb[col]; }
    }
#pragma unroll
    for (int m = 0; m < 8; ++m) {
#pragma unroll
        for (int n = 0; n < 4; ++n) {
            const int col = bn + wc * 64 + n * 16 + li;
#pragma unroll
            for (int i = 0; i < 4; ++i) {
                float v = acc[m][n][i] + bsv[n];
                if (EPI == 2) v = fmaxf(fmaf(v, scv[n], shv[n]), 0.f);
                else if (EPI == 1) v = fmaxf(v, 0.f);
                const int r = bm + wr * 128 + m * 16 + (lane >> 4) * 4 + i;
                if (WF32) Cf[(size_t)r * Nc + col] = v;
                if (WBF16) Cb[(size_t)r * Nc + col] = f2b(v);
            }
        }
    }
}

// ---------------- sparse attention (bf16 qkv): 1 wave per (node, head) ----------------
__global__ __launch_bounds__(256) void attn_sp_k(const u16* __restrict__ qkvb,
                                                 const int* __restrict__ adj,
                                                 const float* __restrict__ wadj,
                                                 const int* __restrict__ cnt,
                                                 u16* __restrict__ ctxb)
{
    const int i = blockIdx.x;
    const int wv = threadIdx.x >> 6, lane = threadIdx.x & 63;
    const int h = blockIdx.y * 4 + wv;
    __shared__ float qs[4][64];
    qs[wv][lane] = b2f((u32)qkvb[(size_t)i * 1536 + h * HD + lane]) * 0.125f;
    __syncthreads();
    int deg = cnt[i];
    if (deg > MAXD) deg = MAXD;
    float m = -3.0e38f, lsum = 0.f, c = 0.f;
    for (int base = 0; base < deg; base += 64) {
        int nn_ = deg - base; if (nn_ > 64) nn_ = 64;
        int j = 0;
        float s = NEGF;
        if (lane < nn_) {
            j = adj[i * MAXD + base + lane];
            const float wgt = wadj[i * MAXD + base + lane];
            const u16* kr = qkvb + (size_t)j * 1536 + DND + h * HD;
            float accd = 0.f;
#pragma unroll
            for (int cq = 0; cq < 4; ++cq) {
                uint4 kv = *reinterpret_cast<const uint4*>(kr + cq * 16);
                const float* qp = &qs[wv][cq * 16];
                accd = fmaf(qp[0],  b2f(kv.x & 0xffffu), accd);
                accd = fmaf(qp[1],  b2f(kv.x >> 16), accd);
                accd = fmaf(qp[2],  b2f(kv.y & 0xffffu), accd);
                accd = fmaf(qp[3],  b2f(kv.y >> 16), accd);
                accd = fmaf(qp[4],  b2f(kv.z & 0xffffu), accd);
                accd = fmaf(qp[5],  b2f(kv.z >> 16), accd);
                accd = fmaf(qp[6],  b2f(kv.w & 0xffffu), accd);
                accd = fmaf(qp[7],  b2f(kv.w >> 16), accd);
                uint4 kv2 = *reinterpret_cast<const uint4*>(kr + cq * 16 + 8);
                accd = fmaf(qp[8],  b2f(kv2.x & 0xffffu), accd);
                accd = fmaf(qp[9],  b2f(kv2.x >> 16), accd);
                accd = fmaf(qp[10], b2f(kv2.y & 0xffffu), accd);
                accd = fmaf(qp[11], b2f(kv2.y >> 16), accd);
                accd = fmaf(qp[12], b2f(kv2.z & 0xffffu), accd);
                accd = fmaf(qp[13], b2f(kv2.z >> 16), accd);
                accd = fmaf(qp[14], b2f(kv2.w & 0xffffu), accd);
                accd = fmaf(qp[15], b2f(kv2.w >> 16), accd);
            }
            s = accd + wgt;
        }
        float mloc = s;
#pragma unroll
        for (int o = 1; o < 64; o <<= 1) mloc = fmaxf(mloc, __shfl_xor(mloc, o, 64));
        const float mnew = fmaxf(m, mloc);
        const float alpha = __expf(m - mnew);
        const float p = (lane < nn_) ? __expf(s - mnew) : 0.f;
        float ps = p;
#pragma unroll
        for (int o = 1; o < 64; o <<= 1) ps += __shfl_xor(ps, o, 64);
        lsum = lsum * alpha + ps;
        c *= alpha;
        for (int l = 0; l < nn_; ++l) {
            const float pj = __shfl(p, l, 64);
            const int jj = __shfl(j, l, 64);
            c = fmaf(pj, b2f((u32)qkvb[(size_t)jj * 1536 + 2 * DND + h * HD + lane]), c);
        }
        m = mnew;
    }
    ctxb[(size_t)i * DND + h * HD + lane] = f2b(c / lsum);
}

// ---------------- host orchestration ----------------
extern "C" void kernel_launch(void* const* d_in, const int* in_sizes, int n_in,
                              void* d_out, int out_size, void* d_ws, size_t ws_size,
                              hipStream_t stream)
{
    const float* x    = (const float*)d_in[0];
    const float* efin = (const float*)d_in[1];
    const float* pos  = (const float*)d_in[2];
    const float* inw  = (const float*)d_in[3];
    const float* inb  = (const float*)d_in[4];
    const float* ow   = (const float*)d_in[5];
    const float* ob   = (const float*)d_in[6];
    const float* etw  = (const float*)d_in[7];
    const float* etb  = (const float*)d_in[8];
    const float* etg  = (const float*)d_in[9];
    const float* etbb = (const float*)d_in[10];
    const float* unw  = (const float*)d_in[11];
    const float* unb  = (const float*)d_in[12];
    const float* uew  = (const float*)d_in[13];
    const float* ueb  = (const float*)d_in[14];
    const int*   ei   = (const int*)d_in[15];

    // workspace layout (offsets in floats) -- R13/R15 layout
    float* W = (float*)d_ws;
    u16*   qkvb  = (u16*)W;                          // union: qkvb bf16 (6.3MB) / te bf16 (33.5MB)
    u16*   te    = (u16*)W;
    int*   rev   = (int*)(W + 8388608);
    u16*   zero  = (u16*)(W + 8421376);              // 1024 u16
    int*   adj   = (int*)(W + 8421888);
    float* wadj  = W + 8684032;
    int*   cnt   = (int*)(W + 8946176);
    int*   oadj  = (int*)(W + 8948224);
    int*   ocnt  = (int*)(W + 9210368);
    int*   iadj  = (int*)(W + 9212416);
    int*   icnt  = (int*)(W + 9474560);
    u16*   ctxb  = (u16*)(W + 9476608);
    u16*   xupdb = (u16*)(W + 10000896);
    u16*   sums  = (u16*)(W + 10525184);
    u16*   nfb   = (u16*)(W + 11049472);             // contiguous: nfb | wbf | efbA
    u16*   wbf   = (u16*)(W + 11573760);             // 5,767,168 u16
    u16*   efbA  = (u16*)(W + 14457344);
    u16*   efbB  = (u16*)(W + 22845952);
    u16*   table = (u16*)efbA;                       // alias: setup-only, 8 MB < 33.5 MB
    // total: 31,234,560 floats = 124.9 MB

    u16* inwb = wbf;
    u16* owb  = wbf + 1572864;
    u16* etwb = wbf + 2097152;
    u16* unwb = wbf + 2621440;
    u16* uewb = wbf + 3670016;

    float* out_nf = (float*)d_out;
    float* out_ef = out_nf + (size_t)NN * DND;

    const int* srcv = ei;
    const int* dstv = ei + EE;

    const u16* WSu = (const u16*)d_ws;
    auto uoff = [&](const void* p) { return (u32)((const u16*)p - WSu); };

    // consolidated setup: 4 dispatches
    setup_init_k<<<NN * NN / 512, 256, 0, stream>>>((u32*)table, adj, wadj, cnt, ocnt, icnt, zero);
    fill_scatter_k<<<EE / 256, 256, 0, stream>>>(ei, table, oadj, ocnt, iadj, icnt);
    rev_csr_k<<<EE / 256, 256, 0, stream>>>(ei, table, pos, rev, adj, wadj, cnt);
    conv_all_k<<<11520, 256, 0, stream>>>(x, inw, ow, etw, unw, uew, efin, nfb);

    for (int l = 0; l < 2; ++l) {
        const u16* efb_cur = l ? efbB : efbA;
        const u16* inwb_l = inwb + (size_t)l * 786432;
        const u16* owb_l  = owb  + (size_t)l * 262144;
        const u16* etwb_l = etwb + (size_t)l * 262144;
        const u16* unwb_l = unwb + (size_t)l * 524288;
        const u16* uewb_l = uewb + (size_t)l * 1048576;
        const float* inb_l  = inb  + (size_t)l * 1536;
        const float* ob_l   = ob   + (size_t)l * 512;
        const float* etb_l  = etb  + (size_t)l * 512;
        const float* etg_l  = etg  + (size_t)l * 512;
        const float* etbb_l = etbb + (size_t)l * 512;
        const float* unb_l  = unb  + (size_t)l * 512;
        const float* ueb_l  = ueb  + (size_t)l * 512;

        // qkv = nf @ inw^T + inb   (bf16 out; te not yet written this layer)
        mgemm_k<0, 0, 0, 1, 12><<<192, 256, 0, stream>>>(
            WSu, uoff(nfb), uoff(inwb_l), inb_l, nullptr, qkvb, NN, 1536, DND,
            0, 0, 0, nullptr, nullptr, nullptr, nullptr, nullptr);

        // sparse masked MHSA -> ctx (bf16)
        attn_sp_k<<<dim3(NN, 2), 256, 0, stream>>>(qkvb, adj, wadj, cnt, ctxb);

        // x_upd = ctx @ ow^T + ob  (bf16)
        mgemm_k<0, 0, 0, 1, 4><<<64, 256, 0, stream>>>(
            WSu, uoff(ctxb), uoff(owb_l), ob_l, nullptr, xupdb, NN, DND, DND,
            0, 0, 0, nullptr, nullptr, nullptr, nullptr, nullptr);

        // te = relu(BN(ef @ etw^T + etb))  (bf16, 256^2; overwrites dead qkvb)
        mgemm256_k<0, 2, 0, 1><<<256, 512, 0, stream>>>(
            WSu, uoff(efb_cur), uoff(etwb_l), etb_l, nullptr, te, EE, DND, DND,
            0, 0, 0, nullptr, nullptr, nullptr, etg_l, etbb_l);

        // sums = bf16(max_out te + max_in te)
        gather_max_k<<<NN, 256, 0, stream>>>(te, oadj, ocnt, iadj, icnt, sums);

        // ef_next = (relu?)([nf[src], ef, ef[rev], nf[dst]] @ uew^T + ueb)  (256^2)
        if (l == 0)
            mgemm256_k<1, 1, 0, 1><<<256, 512, 0, stream>>>(
                WSu, 0, uoff(uewb_l), ueb_l, nullptr, efbB, EE, DND, 2048,
                uoff(nfb), uoff(efb_cur), uoff(zero), srcv, dstv, rev, nullptr, nullptr);
        else
            mgemm256_k<1, 0, 1, 0><<<256, 512, 0, stream>>>(
                WSu, 0, uoff(uewb_l), ueb_l, out_ef, nullptr, EE, DND, 2048,
                uoff(nfb), uoff(efb_cur), uoff(zero), srcv, dstv, rev, nullptr, nullptr);

        // nf_next = (relu?)([x_upd, subj+obj] @ unw^T + unb)
        if (l == 0)
            mgemm_k<2, 1, 0, 1, 4><<<64, 256, 0, stream>>>(
                WSu, 0, uoff(unwb_l), unb_l, nullptr, nfb, NN, DND, 1024,
                uoff(xupdb), uoff(sums), 0, nullptr, nullptr, nullptr, nullptr, nullptr);
        else
            mgemm_k<2, 0, 1, 0, 4><<<64, 256, 0, stream>>>(
                WSu, 0, uoff(unwb_l), unb_l, out_nf, nullptr, NN, DND, 1024,
                uoff(xupdb), uoff(sums), 0, nullptr, nullptr, nullptr, nullptr, nullptr);
    }
}